// Round 1
// baseline (7336.514 us; speedup 1.0000x reference)
//
#include <hip/hip_runtime.h>

#define DIM 256
#define N_REL 8

// ---------------------------------------------------------------------------
// y = relu(x @ W + b)   x:[M,256] row-major, W:[256,256] row-major (in,out)
// Block tile 128(M) x 128(N), 256 threads, 8x8 per thread, K-step 16.
// ---------------------------------------------------------------------------
__global__ __launch_bounds__(256) void gemm_bias_relu(
    const float* __restrict__ A, const float* __restrict__ B,
    const float* __restrict__ bias, float* __restrict__ Y, int M)
{
    __shared__ float As[16][132];   // [k][m], padded stride
    __shared__ float Bs[16][128];   // [k][n]

    const int t  = threadIdx.x;
    const int tx = t & 15;          // 16 col-threads
    const int ty = t >> 4;          // 16 row-threads
    const int row0 = blockIdx.x * 128;
    const int col0 = blockIdx.y * 128;

    float acc[8][8];
#pragma unroll
    for (int i = 0; i < 8; i++)
#pragma unroll
        for (int j = 0; j < 8; j++) acc[i][j] = 0.f;

    // A staging: 128 rows x 16 k = 512 float4; thread t handles f = t, t+256
    const int arow  = t >> 2;            // 0..63
    const int akseg = (t & 3) * 4;       // k offset 0,4,8,12
    // B staging: 16 k x 128 cols = 512 float4; thread t handles krow t>>5 (+8)
    const int bk0  = t >> 5;             // 0..7
    const int bcol = (t & 31) * 4;       // 0..124

    for (int k0 = 0; k0 < DIM; k0 += 16) {
#pragma unroll
        for (int h = 0; h < 2; h++) {
            const int row = row0 + arow + h * 64;
            float4 av;
            if (row < M) av = *(const float4*)(A + (size_t)row * DIM + k0 + akseg);
            else         av = make_float4(0.f, 0.f, 0.f, 0.f);
            As[akseg + 0][arow + h * 64] = av.x;
            As[akseg + 1][arow + h * 64] = av.y;
            As[akseg + 2][arow + h * 64] = av.z;
            As[akseg + 3][arow + h * 64] = av.w;
        }
#pragma unroll
        for (int h = 0; h < 2; h++) {
            const int krow = bk0 + h * 8;
            *(float4*)&Bs[krow][bcol] =
                *(const float4*)(B + (size_t)(k0 + krow) * DIM + col0 + bcol);
        }
        __syncthreads();

#pragma unroll
        for (int k = 0; k < 16; k++) {
            float a[8], b[8];
            *(float4*)&a[0] = *(const float4*)&As[k][ty * 4];
            *(float4*)&a[4] = *(const float4*)&As[k][64 + ty * 4];
            *(float4*)&b[0] = *(const float4*)&Bs[k][tx * 4];
            *(float4*)&b[4] = *(const float4*)&Bs[k][64 + tx * 4];
#pragma unroll
            for (int i = 0; i < 8; i++)
#pragma unroll
                for (int j = 0; j < 8; j++)
                    acc[i][j] = fmaf(a[i], b[j], acc[i][j]);
        }
        __syncthreads();
    }

    // epilogue: bias + relu, vectorized stores
#pragma unroll
    for (int im = 0; im < 2; im++) {
#pragma unroll
        for (int i = 0; i < 4; i++) {
            const int row = row0 + im * 64 + ty * 4 + i;
            if (row >= M) continue;
#pragma unroll
            for (int jm = 0; jm < 2; jm++) {
                const int col = col0 + jm * 64 + tx * 4;
                const float4 bb = *(const float4*)(bias + col);
                float4 o;
                o.x = fmaxf(acc[im * 4 + i][jm * 4 + 0] + bb.x, 0.f);
                o.y = fmaxf(acc[im * 4 + i][jm * 4 + 1] + bb.y, 0.f);
                o.z = fmaxf(acc[im * 4 + i][jm * 4 + 2] + bb.z, 0.f);
                o.w = fmaxf(acc[im * 4 + i][jm * 4 + 3] + bb.w, 0.f);
                *(float4*)(Y + (size_t)row * DIM + col) = o;
            }
        }
    }
}

// ---------------------------------------------------------------------------
// For every edge e with et[e]==rel:  out[dst[e]][:] += y[src[e]][:]
// One wave per edge (grid-stride over edges); lane l handles 4 floats.
// ---------------------------------------------------------------------------
__global__ __launch_bounds__(256) void scatter_rel(
    const float* __restrict__ y, const int* __restrict__ src,
    const int* __restrict__ dst, const int* __restrict__ et,
    int rel, float* __restrict__ out, int n_edges)
{
    const int lane   = threadIdx.x & 63;
    const int wave   = (blockIdx.x * blockDim.x + threadIdx.x) >> 6;
    const int nwaves = (gridDim.x * blockDim.x) >> 6;

    for (int e = wave; e < n_edges; e += nwaves) {
        if (et[e] != rel) continue;
        const int s = src[e];
        const int d = dst[e];
        const float4 v = *(const float4*)(y + (size_t)s * DIM + lane * 4);
        float* o = out + (size_t)d * DIM + lane * 4;
        atomicAdd(o + 0, v.x);
        atomicAdd(o + 1, v.y);
        atomicAdd(o + 2, v.z);
        atomicAdd(o + 3, v.w);
    }
}

extern "C" void kernel_launch(void* const* d_in, const int* in_sizes, int n_in,
                              void* d_out, int out_size, void* d_ws, size_t ws_size,
                              hipStream_t stream)
{
    const float* x   = (const float*)d_in[0];
    const float* W0  = (const float*)d_in[1];
    const float* b0  = (const float*)d_in[2];
    const float* W1  = (const float*)d_in[3];
    const float* b1  = (const float*)d_in[4];
    const int*  eidx = (const int*)d_in[5];
    const int*  etyp = (const int*)d_in[6];

    const int M       = in_sizes[0] / DIM;      // 50000
    const int n_edges = in_sizes[6];            // 800000
    const int* src = eidx;
    const int* dst = eidx + n_edges;

    float* out = (float*)d_out;
    float* h1  = (float*)d_ws;                          // M*DIM floats
    float* y   = (float*)d_ws + (size_t)M * DIM;        // M*DIM floats

    const dim3 gblk(256), ggrid((M + 127) / 128, DIM / 128);
    const dim3 sblk(256), sgrid(1024);

    // ---- layer 1: h1 = segment_sum(relu(x @ W0[r] + b0)[src] -> dst) ----
    hipMemsetAsync(h1, 0, (size_t)M * DIM * sizeof(float), stream);
    for (int r = 0; r < N_REL; r++) {
        gemm_bias_relu<<<ggrid, gblk, 0, stream>>>(x, W0 + (size_t)r * DIM * DIM, b0, y, M);
        scatter_rel<<<sgrid, sblk, 0, stream>>>(y, src, dst, etyp, r, h1, n_edges);
    }

    // ---- layer 2: out = segment_sum(relu(h1 @ W1[r] + b1)[src] -> dst) ----
    hipMemsetAsync(out, 0, (size_t)M * DIM * sizeof(float), stream);
    for (int r = 0; r < N_REL; r++) {
        gemm_bias_relu<<<ggrid, gblk, 0, stream>>>(h1, W1 + (size_t)r * DIM * DIM, b1, y, M);
        scatter_rel<<<sgrid, sblk, 0, stream>>>(y, src, dst, etyp, r, out, n_edges);
    }
}

// Round 2
// 2039.307 us; speedup vs baseline: 3.5976x; 3.5976x over previous
//
#include <hip/hip_runtime.h>

#define DIM 256
#define N_REL 8

// ---------------- bf16 helpers (manual, RNE) ----------------
__device__ inline unsigned short f2bf(float f) {
    unsigned u = __float_as_uint(f);
    u += 0x7FFFu + ((u >> 16) & 1u);
    return (unsigned short)(u >> 16);
}
__device__ inline float bf2f(unsigned short h) {
    return __uint_as_float(((unsigned)h) << 16);
}

template <typename YT> __device__ inline void store_y4(YT* p, float4 v);
template <> __device__ inline void store_y4<float>(float* p, float4 v) {
    *(float4*)p = v;
}
template <> __device__ inline void store_y4<unsigned short>(unsigned short* p, float4 v) {
    ushort4 o;
    o.x = f2bf(v.x); o.y = f2bf(v.y); o.z = f2bf(v.z); o.w = f2bf(v.w);
    *(ushort4*)p = o;
}
template <typename YT> __device__ inline float4 load_y4(const YT* p);
template <> __device__ inline float4 load_y4<float>(const float* p) {
    return *(const float4*)p;
}
template <> __device__ inline float4 load_y4<unsigned short>(const unsigned short* p) {
    ushort4 u = *(const ushort4*)p;
    return make_float4(bf2f(u.x), bf2f(u.y), bf2f(u.z), bf2f(u.w));
}

// ---------------------------------------------------------------------------
// y = relu(x @ W + b)   x:[M,256] row-major, W:[256,256] row-major (in,out)
// Block tile 128(M) x 128(N), 256 threads, 8x8 per thread, K-step 16.
// ---------------------------------------------------------------------------
template <typename YT>
__global__ __launch_bounds__(256) void gemm_bias_relu(
    const float* __restrict__ A, const float* __restrict__ B,
    const float* __restrict__ bias, YT* __restrict__ Y, int M)
{
    __shared__ float As[16][132];
    __shared__ float Bs[16][128];

    const int t  = threadIdx.x;
    const int tx = t & 15;
    const int ty = t >> 4;
    const int row0 = blockIdx.x * 128;
    const int col0 = blockIdx.y * 128;

    float acc[8][8];
#pragma unroll
    for (int i = 0; i < 8; i++)
#pragma unroll
        for (int j = 0; j < 8; j++) acc[i][j] = 0.f;

    const int arow  = t >> 2;
    const int akseg = (t & 3) * 4;
    const int bk0  = t >> 5;
    const int bcol = (t & 31) * 4;

    for (int k0 = 0; k0 < DIM; k0 += 16) {
#pragma unroll
        for (int h = 0; h < 2; h++) {
            const int row = row0 + arow + h * 64;
            float4 av;
            if (row < M) av = *(const float4*)(A + (size_t)row * DIM + k0 + akseg);
            else         av = make_float4(0.f, 0.f, 0.f, 0.f);
            As[akseg + 0][arow + h * 64] = av.x;
            As[akseg + 1][arow + h * 64] = av.y;
            As[akseg + 2][arow + h * 64] = av.z;
            As[akseg + 3][arow + h * 64] = av.w;
        }
#pragma unroll
        for (int h = 0; h < 2; h++) {
            const int krow = bk0 + h * 8;
            *(float4*)&Bs[krow][bcol] =
                *(const float4*)(B + (size_t)(k0 + krow) * DIM + col0 + bcol);
        }
        __syncthreads();

#pragma unroll
        for (int k = 0; k < 16; k++) {
            float a[8], b[8];
            *(float4*)&a[0] = *(const float4*)&As[k][ty * 4];
            *(float4*)&a[4] = *(const float4*)&As[k][64 + ty * 4];
            *(float4*)&b[0] = *(const float4*)&Bs[k][tx * 4];
            *(float4*)&b[4] = *(const float4*)&Bs[k][64 + tx * 4];
#pragma unroll
            for (int i = 0; i < 8; i++)
#pragma unroll
                for (int j = 0; j < 8; j++)
                    acc[i][j] = fmaf(a[i], b[j], acc[i][j]);
        }
        __syncthreads();
    }

#pragma unroll
    for (int im = 0; im < 2; im++) {
#pragma unroll
        for (int i = 0; i < 4; i++) {
            const int row = row0 + im * 64 + ty * 4 + i;
            if (row >= M) continue;
#pragma unroll
            for (int jm = 0; jm < 2; jm++) {
                const int col = col0 + jm * 64 + tx * 4;
                const float4 bb = *(const float4*)(bias + col);
                float4 o;
                o.x = fmaxf(acc[im * 4 + i][jm * 4 + 0] + bb.x, 0.f);
                o.y = fmaxf(acc[im * 4 + i][jm * 4 + 1] + bb.y, 0.f);
                o.z = fmaxf(acc[im * 4 + i][jm * 4 + 2] + bb.z, 0.f);
                o.w = fmaxf(acc[im * 4 + i][jm * 4 + 3] + bb.w, 0.f);
                store_y4<YT>(Y + (size_t)row * DIM + col, o);
            }
        }
    }
}

// ---------------- CSR build: histogram -> scan -> fill ----------------
__global__ __launch_bounds__(256) void count_dst(
    const int* __restrict__ dst, int E, int* __restrict__ cnt)
{
    const int e = blockIdx.x * blockDim.x + threadIdx.x;
    if (e < E) atomicAdd(&cnt[dst[e]], 1);
}

__global__ __launch_bounds__(1024) void scan_counts(
    const int* __restrict__ cnt, int N, int* __restrict__ rowptr,
    int* __restrict__ cursor)
{
    __shared__ int part[1024];
    const int t = threadIdx.x;
    const int chunk = (N + 1023) / 1024;
    const int lo = t * chunk;
    const int hi = min(lo + chunk, N);
    int s = 0;
    for (int i = lo; i < hi; i++) s += cnt[i];
    part[t] = s;
    __syncthreads();
    for (int off = 1; off < 1024; off <<= 1) {
        const int v = part[t];
        const int add = (t >= off) ? part[t - off] : 0;
        __syncthreads();
        part[t] = v + add;
        __syncthreads();
    }
    int run = (t == 0) ? 0 : part[t - 1];
    for (int i = lo; i < hi; i++) {
        const int c = cnt[i];
        rowptr[i] = run;
        cursor[i] = run;
        run += c;
    }
    if (t == 1023) rowptr[N] = part[1023];
}

__global__ __launch_bounds__(256) void fill_edges(
    const int* __restrict__ src, const int* __restrict__ dst,
    const int* __restrict__ et, int E, int* __restrict__ cursor,
    unsigned* __restrict__ ep)
{
    const int e = blockIdx.x * blockDim.x + threadIdx.x;
    if (e >= E) return;
    const int pos = atomicAdd(&cursor[dst[e]], 1);
    ep[pos] = (unsigned)src[e] | ((unsigned)et[e] << 16);
}

// ---------------------------------------------------------------------------
// out[d][:] = sum over incoming edges (src,rel) of yall[rel][src][:]
// One wave per dst node; lane handles 4 floats. No atomics.
// ---------------------------------------------------------------------------
template <typename YT>
__global__ __launch_bounds__(256) void aggregate(
    const YT* __restrict__ yall, const unsigned* __restrict__ ep,
    const int* __restrict__ rowptr, float* __restrict__ out, int M)
{
    const int lane = threadIdx.x & 63;
    int w = (blockIdx.x * blockDim.x + threadIdx.x) >> 6;
    const int nw = (gridDim.x * blockDim.x) >> 6;
    const size_t plane = (size_t)M * DIM;
    for (int d = w; d < M; d += nw) {
        const int beg = rowptr[d];
        const int end = rowptr[d + 1];
        float4 acc = make_float4(0.f, 0.f, 0.f, 0.f);
        for (int c = beg; c < end; c += 64) {
            const int n = min(64, end - c);
            const unsigned myep = (c + lane < end) ? ep[c + lane] : 0u;
            for (int i = 0; i < n; i++) {
                const unsigned p = __shfl(myep, i);
                const size_t rowoff =
                    (size_t)(p >> 16) * plane + (size_t)(p & 0xFFFFu) * DIM;
                const float4 v = load_y4<YT>(yall + rowoff + lane * 4);
                acc.x += v.x; acc.y += v.y; acc.z += v.z; acc.w += v.w;
            }
        }
        *(float4*)(out + (size_t)d * DIM + lane * 4) = acc;
    }
}

// ---------------- fallback (round-1 atomic scatter) ----------------
__global__ __launch_bounds__(256) void scatter_rel(
    const float* __restrict__ y, const int* __restrict__ src,
    const int* __restrict__ dst, const int* __restrict__ et,
    int rel, float* __restrict__ out, int n_edges)
{
    const int lane   = threadIdx.x & 63;
    const int wave   = (blockIdx.x * blockDim.x + threadIdx.x) >> 6;
    const int nwaves = (gridDim.x * blockDim.x) >> 6;
    for (int e = wave; e < n_edges; e += nwaves) {
        if (et[e] != rel) continue;
        const int s = src[e];
        const int d = dst[e];
        const float4 v = *(const float4*)(y + (size_t)s * DIM + lane * 4);
        float* o = out + (size_t)d * DIM + lane * 4;
        atomicAdd(o + 0, v.x);
        atomicAdd(o + 1, v.y);
        atomicAdd(o + 2, v.z);
        atomicAdd(o + 3, v.w);
    }
}

static inline size_t align16(size_t x) { return (x + 15) & ~(size_t)15; }

template <typename YT>
static void run_pipeline(const float* x, const float* W0, const float* b0,
                         const float* W1, const float* b1,
                         const int* src, const int* dst, const int* et,
                         int M, int E, float* out, char* ws, hipStream_t stream)
{
    size_t off = 0;
    float* h1 = (float*)(ws + off);          off = align16(off + (size_t)M * DIM * 4);
    int* rowptr = (int*)(ws + off);          off = align16(off + (size_t)(M + 1) * 4);
    int* cnt = (int*)(ws + off);             off = align16(off + (size_t)M * 4);
    int* cursor = (int*)(ws + off);          off = align16(off + (size_t)M * 4);
    unsigned* ep = (unsigned*)(ws + off);    off = align16(off + (size_t)E * 4);
    YT* yall = (YT*)(ws + off);

    const size_t plane = (size_t)M * DIM;

    // CSR build (once; shared by both layers)
    hipMemsetAsync(cnt, 0, (size_t)M * 4, stream);
    count_dst<<<(E + 255) / 256, 256, 0, stream>>>(dst, E, cnt);
    scan_counts<<<1, 1024, 0, stream>>>(cnt, M, rowptr, cursor);
    fill_edges<<<(E + 255) / 256, 256, 0, stream>>>(src, dst, et, E, cursor, ep);

    const dim3 gblk(256), ggrid((M + 127) / 128, DIM / 128);
    const int ablk = 256;
    const int agrid = (M * 64 + ablk - 1) / ablk;

    // layer 1
    for (int r = 0; r < N_REL; r++)
        gemm_bias_relu<YT><<<ggrid, gblk, 0, stream>>>(
            x, W0 + (size_t)r * DIM * DIM, b0, yall + (size_t)r * plane, M);
    aggregate<YT><<<agrid, ablk, 0, stream>>>(yall, ep, rowptr, h1, M);

    // layer 2
    for (int r = 0; r < N_REL; r++)
        gemm_bias_relu<YT><<<ggrid, gblk, 0, stream>>>(
            h1, W1 + (size_t)r * DIM * DIM, b1, yall + (size_t)r * plane, M);
    aggregate<YT><<<agrid, ablk, 0, stream>>>(yall, ep, rowptr, out, M);
}

extern "C" void kernel_launch(void* const* d_in, const int* in_sizes, int n_in,
                              void* d_out, int out_size, void* d_ws, size_t ws_size,
                              hipStream_t stream)
{
    const float* x   = (const float*)d_in[0];
    const float* W0  = (const float*)d_in[1];
    const float* b0  = (const float*)d_in[2];
    const float* W1  = (const float*)d_in[3];
    const float* b1  = (const float*)d_in[4];
    const int*  eidx = (const int*)d_in[5];
    const int*  etyp = (const int*)d_in[6];

    const int M = in_sizes[0] / DIM;   // 50000
    const int E = in_sizes[6];         // 800000
    const int* src = eidx;
    const int* dst = eidx + E;
    float* out = (float*)d_out;

    const size_t plane = (size_t)M * DIM;
    const size_t fixed = align16(plane * 4) + align16((size_t)(M + 1) * 4) +
                         2 * align16((size_t)M * 4) + align16((size_t)E * 4);
    const size_t need_f32  = fixed + N_REL * plane * 4;
    const size_t need_bf16 = fixed + N_REL * plane * 2;

    if (M < 65536 && ws_size >= need_f32) {
        run_pipeline<float>(x, W0, b0, W1, b1, src, dst, etyp, M, E, out,
                            (char*)d_ws, stream);
    } else if (M < 65536 && ws_size >= need_bf16) {
        run_pipeline<unsigned short>(x, W0, b0, W1, b1, src, dst, etyp, M, E, out,
                                     (char*)d_ws, stream);
    } else {
        // fallback: round-1 per-relation atomic scatter
        float* h1 = (float*)d_ws;
        float* y  = (float*)d_ws + plane;
        const dim3 gblk(256), ggrid((M + 127) / 128, DIM / 128);
        hipMemsetAsync(h1, 0, plane * 4, stream);
        for (int r = 0; r < N_REL; r++) {
            gemm_bias_relu<float><<<ggrid, gblk, 0, stream>>>(
                x, W0 + (size_t)r * DIM * DIM, b0, y, M);
            scatter_rel<<<1024, 256, 0, stream>>>(y, src, dst, etyp, r, h1, E);
        }
        hipMemsetAsync(out, 0, plane * 4, stream);
        for (int r = 0; r < N_REL; r++) {
            gemm_bias_relu<float><<<ggrid, gblk, 0, stream>>>(
                h1, W1 + (size_t)r * DIM * DIM, b1, y, M);
            scatter_rel<<<1024, 256, 0, stream>>>(y, src, dst, etyp, r, out, E);
        }
    }
}

// Round 3
// 905.556 us; speedup vs baseline: 8.1017x; 2.2520x over previous
//
#include <hip/hip_runtime.h>

#define DIM 256
#define N_REL 8

typedef __attribute__((ext_vector_type(8))) short short8_t;
typedef __attribute__((ext_vector_type(4))) float float4_t;

// ---------------- bf16 helpers (manual, RNE) ----------------
__device__ inline unsigned short f2bf(float f) {
    unsigned u = __float_as_uint(f);
    u += 0x7FFFu + ((u >> 16) & 1u);
    return (unsigned short)(u >> 16);
}
__device__ inline float bf2f(unsigned short h) {
    return __uint_as_float(((unsigned)h) << 16);
}

// ---------------- cast / transpose prep kernels ----------------
__global__ __launch_bounds__(256) void cast_f32_bf16(
    const float* __restrict__ in, unsigned short* __restrict__ out, int n4)
{
    const int i = blockIdx.x * blockDim.x + threadIdx.x;
    if (i >= n4) return;
    const float4 v = ((const float4*)in)[i];
    ushort4 o;
    o.x = f2bf(v.x); o.y = f2bf(v.y); o.z = f2bf(v.z); o.w = f2bf(v.w);
    ((ushort4*)out)[i] = o;
}

// W[rel][in][out] f32  ->  Wt[rel][out][in] bf16
__global__ __launch_bounds__(256) void transpose_cast_w(
    const float* __restrict__ W, unsigned short* __restrict__ Wt)
{
    __shared__ float tile[32][33];
    const int rel = blockIdx.z;
    const int i0 = blockIdx.x * 32, o0 = blockIdx.y * 32;
    const int tx = threadIdx.x, ty = threadIdx.y;   // (32, 8)
    const float* Wr = W + (size_t)rel * DIM * DIM;
    unsigned short* Wtr = Wt + (size_t)rel * DIM * DIM;
#pragma unroll
    for (int j = 0; j < 4; j++)
        tile[ty + 8 * j][tx] = Wr[(size_t)(i0 + ty + 8 * j) * DIM + o0 + tx];
    __syncthreads();
#pragma unroll
    for (int j = 0; j < 4; j++)
        Wtr[(size_t)(o0 + ty + 8 * j) * DIM + i0 + tx] = f2bf(tile[tx][ty + 8 * j]);
}

// ---------------------------------------------------------------------------
// Yall[rel] = relu(Xb @ W[rel] + bias) in bf16.
// Xb:[M][256] bf16, Wtb:[R][out][in] bf16 (transposed), tile 128x128, BK=32,
// 4 waves of 64x64 (4x4 mfma_f32_16x16x32_bf16), LDS stride 40 (2-way = free).
// ---------------------------------------------------------------------------
__global__ __launch_bounds__(256) void gemm_mfma_bias_relu(
    const unsigned short* __restrict__ Xb,
    const unsigned short* __restrict__ Wtb,
    const float* __restrict__ bias,
    unsigned short* __restrict__ Yall, int M)
{
    __shared__ __align__(16) short As[128 * 40];
    __shared__ __align__(16) short Bs[128 * 40];

    const int t = threadIdx.x;
    const int m0 = blockIdx.x * 128;
    const int n0 = blockIdx.y * 128;
    const int rel = blockIdx.z;

    const unsigned short* Wt = Wtb + (size_t)rel * DIM * DIM;
    unsigned short* Y = Yall + (size_t)rel * M * DIM;

    const int lane = t & 63;
    const int w = t >> 6;
    const int wr = w & 1, wc = w >> 1;
    const int r = lane & 15, q = lane >> 4;

    const int rowA0 = t >> 2;     // 0..63 (staging row; +64 for second half)
    const int segA0 = t & 3;      // 16B segment within 64B row

    float4_t acc[4][4];
#pragma unroll
    for (int i = 0; i < 4; i++)
#pragma unroll
        for (int j = 0; j < 4; j++) {
            float4_t z = {0.f, 0.f, 0.f, 0.f};
            acc[i][j] = z;
        }

    short8_t ra[2], rb[2];
    const short8_t zero8 = {0, 0, 0, 0, 0, 0, 0, 0};

#define LOAD_TILES(ks)                                                           \
    {                                                                            \
        const int k0_ = (ks) * 32;                                               \
        _Pragma("unroll")                                                        \
        for (int h = 0; h < 2; h++) {                                            \
            const int row_ = rowA0 + h * 64;                                     \
            const int m_ = m0 + row_;                                            \
            if (m_ < M)                                                          \
                ra[h] = *(const short8_t*)(Xb + (size_t)m_ * DIM + k0_ + segA0 * 8); \
            else                                                                 \
                ra[h] = zero8;                                                   \
            rb[h] = *(const short8_t*)(Wt + (size_t)(n0 + row_) * DIM + k0_ + segA0 * 8); \
        }                                                                        \
    }

    LOAD_TILES(0);
#pragma unroll 1
    for (int ks = 0; ks < 8; ks++) {
#pragma unroll
        for (int h = 0; h < 2; h++) {
            const int row_ = rowA0 + h * 64;
            *(short8_t*)&As[row_ * 40 + segA0 * 8] = ra[h];
            *(short8_t*)&Bs[row_ * 40 + segA0 * 8] = rb[h];
        }
        __syncthreads();
        if (ks < 7) LOAD_TILES(ks + 1);

        short8_t af[4], bf[4];
#pragma unroll
        for (int mi = 0; mi < 4; mi++)
            af[mi] = *(const short8_t*)&As[(wr * 64 + mi * 16 + r) * 40 + q * 8];
#pragma unroll
        for (int ni = 0; ni < 4; ni++)
            bf[ni] = *(const short8_t*)&Bs[(wc * 64 + ni * 16 + r) * 40 + q * 8];
#pragma unroll
        for (int mi = 0; mi < 4; mi++)
#pragma unroll
            for (int ni = 0; ni < 4; ni++)
                acc[mi][ni] = __builtin_amdgcn_mfma_f32_16x16x32_bf16(
                    af[mi], bf[ni], acc[mi][ni], 0, 0, 0);
        __syncthreads();
    }
#undef LOAD_TILES

    // epilogue: bias + relu, bf16 store. C/D: col=lane&15, row=quad*4+reg (m89)
#pragma unroll
    for (int ni = 0; ni < 4; ni++) {
        const int col = n0 + wc * 64 + ni * 16 + r;
        const float bb = bias[col];
#pragma unroll
        for (int mi = 0; mi < 4; mi++) {
#pragma unroll
            for (int e = 0; e < 4; e++) {
                const int row = m0 + wr * 64 + mi * 16 + q * 4 + e;
                if (row < M)
                    Y[(size_t)row * DIM + col] = f2bf(fmaxf(acc[mi][ni][e] + bb, 0.f));
            }
        }
    }
}

// ---------------- CSR build: histogram -> scan -> fill ----------------
__global__ __launch_bounds__(256) void count_dst(
    const int* __restrict__ dst, int E, int* __restrict__ cnt)
{
    const int e = blockIdx.x * blockDim.x + threadIdx.x;
    if (e < E) atomicAdd(&cnt[dst[e]], 1);
}

__global__ __launch_bounds__(1024) void scan_counts(
    const int* __restrict__ cnt, int N, int* __restrict__ rowptr,
    int* __restrict__ cursor)
{
    __shared__ int part[1024];
    const int t = threadIdx.x;
    const int chunk = (N + 1023) / 1024;
    const int lo = t * chunk;
    const int hi = min(lo + chunk, N);
    int s = 0;
    for (int i = lo; i < hi; i++) s += cnt[i];
    part[t] = s;
    __syncthreads();
    for (int off = 1; off < 1024; off <<= 1) {
        const int v = part[t];
        const int add = (t >= off) ? part[t - off] : 0;
        __syncthreads();
        part[t] = v + add;
        __syncthreads();
    }
    int run = (t == 0) ? 0 : part[t - 1];
    for (int i = lo; i < hi; i++) {
        const int c = cnt[i];
        rowptr[i] = run;
        cursor[i] = run;
        run += c;
    }
    if (t == 1023) rowptr[N] = part[1023];
}

__global__ __launch_bounds__(256) void fill_edges(
    const int* __restrict__ src, const int* __restrict__ dst,
    const int* __restrict__ et, int E, int* __restrict__ cursor,
    unsigned* __restrict__ ep)
{
    const int e = blockIdx.x * blockDim.x + threadIdx.x;
    if (e >= E) return;
    const int pos = atomicAdd(&cursor[dst[e]], 1);
    ep[pos] = (unsigned)src[e] | ((unsigned)et[e] << 16);
}

// ---------------- aggregate: gather + sum, no atomics ----------------
__device__ inline void store_out4(float* p, float4 v) { *(float4*)p = v; }
__device__ inline void store_out4(unsigned short* p, float4 v) {
    ushort4 o;
    o.x = f2bf(v.x); o.y = f2bf(v.y); o.z = f2bf(v.z); o.w = f2bf(v.w);
    *(ushort4*)p = o;
}

template <typename OT>
__global__ __launch_bounds__(256) void aggregate_bf16(
    const unsigned short* __restrict__ yall, const unsigned* __restrict__ ep,
    const int* __restrict__ rowptr, OT* __restrict__ out, int M)
{
    const int lane = threadIdx.x & 63;
    const int wv = (blockIdx.x * blockDim.x + threadIdx.x) >> 6;
    const int nw = (gridDim.x * blockDim.x) >> 6;
    const size_t plane = (size_t)M * DIM;
    for (int d = wv; d < M; d += nw) {
        const int beg = rowptr[d], end = rowptr[d + 1];
        float4 acc = make_float4(0.f, 0.f, 0.f, 0.f);
        for (int c = beg; c < end; c += 64) {
            const int n = min(64, end - c);
            const unsigned myep = (c + lane < end) ? ep[c + lane] : 0u;
            for (int i = 0; i < n; i++) {
                const unsigned p = __shfl(myep, i);
                const unsigned short* yr = yall + (size_t)(p >> 16) * plane +
                                           (size_t)(p & 0xFFFFu) * DIM + lane * 4;
                const ushort4 u = *(const ushort4*)yr;
                acc.x += bf2f(u.x); acc.y += bf2f(u.y);
                acc.z += bf2f(u.z); acc.w += bf2f(u.w);
            }
        }
        store_out4(out + (size_t)d * DIM + lane * 4, acc);
    }
}

// ---------------- fallback: fp32 vector GEMM + atomic scatter ----------------
__global__ __launch_bounds__(256) void gemm_bias_relu_f32(
    const float* __restrict__ A, const float* __restrict__ B,
    const float* __restrict__ bias, float* __restrict__ Y, int M)
{
    __shared__ float Asf[16][132];
    __shared__ float Bsf[16][128];
    const int t = threadIdx.x;
    const int tx = t & 15, ty = t >> 4;
    const int row0 = blockIdx.x * 128, col0 = blockIdx.y * 128;
    float acc[8][8];
#pragma unroll
    for (int i = 0; i < 8; i++)
#pragma unroll
        for (int j = 0; j < 8; j++) acc[i][j] = 0.f;
    const int arow = t >> 2, akseg = (t & 3) * 4;
    const int bk0 = t >> 5, bcol = (t & 31) * 4;
    for (int k0 = 0; k0 < DIM; k0 += 16) {
#pragma unroll
        for (int h = 0; h < 2; h++) {
            const int row = row0 + arow + h * 64;
            float4 av = (row < M) ? *(const float4*)(A + (size_t)row * DIM + k0 + akseg)
                                  : make_float4(0, 0, 0, 0);
            Asf[akseg + 0][arow + h * 64] = av.x;
            Asf[akseg + 1][arow + h * 64] = av.y;
            Asf[akseg + 2][arow + h * 64] = av.z;
            Asf[akseg + 3][arow + h * 64] = av.w;
        }
#pragma unroll
        for (int h = 0; h < 2; h++) {
            const int krow = bk0 + h * 8;
            *(float4*)&Bsf[krow][bcol] =
                *(const float4*)(B + (size_t)(k0 + krow) * DIM + col0 + bcol);
        }
        __syncthreads();
#pragma unroll
        for (int k = 0; k < 16; k++) {
            float a[8], b[8];
            *(float4*)&a[0] = *(const float4*)&Asf[k][ty * 4];
            *(float4*)&a[4] = *(const float4*)&Asf[k][64 + ty * 4];
            *(float4*)&b[0] = *(const float4*)&Bsf[k][tx * 4];
            *(float4*)&b[4] = *(const float4*)&Bsf[k][64 + tx * 4];
#pragma unroll
            for (int i = 0; i < 8; i++)
#pragma unroll
                for (int j = 0; j < 8; j++) acc[i][j] = fmaf(a[i], b[j], acc[i][j]);
        }
        __syncthreads();
    }
#pragma unroll
    for (int im = 0; im < 2; im++)
#pragma unroll
        for (int i = 0; i < 4; i++) {
            const int row = row0 + im * 64 + ty * 4 + i;
            if (row >= M) continue;
#pragma unroll
            for (int jm = 0; jm < 2; jm++) {
                const int col = col0 + jm * 64 + tx * 4;
                const float4 bb = *(const float4*)(bias + col);
                float4 o;
                o.x = fmaxf(acc[im * 4 + i][jm * 4 + 0] + bb.x, 0.f);
                o.y = fmaxf(acc[im * 4 + i][jm * 4 + 1] + bb.y, 0.f);
                o.z = fmaxf(acc[im * 4 + i][jm * 4 + 2] + bb.z, 0.f);
                o.w = fmaxf(acc[im * 4 + i][jm * 4 + 3] + bb.w, 0.f);
                *(float4*)(Y + (size_t)row * DIM + col) = o;
            }
        }
}

__global__ __launch_bounds__(256) void scatter_rel(
    const float* __restrict__ y, const int* __restrict__ src,
    const int* __restrict__ dst, const int* __restrict__ et,
    int rel, float* __restrict__ out, int n_edges)
{
    const int lane = threadIdx.x & 63;
    const int wave = (blockIdx.x * blockDim.x + threadIdx.x) >> 6;
    const int nwaves = (gridDim.x * blockDim.x) >> 6;
    for (int e = wave; e < n_edges; e += nwaves) {
        if (et[e] != rel) continue;
        const float4 v = *(const float4*)(y + (size_t)src[e] * DIM + lane * 4);
        float* o = out + (size_t)dst[e] * DIM + lane * 4;
        atomicAdd(o + 0, v.x);
        atomicAdd(o + 1, v.y);
        atomicAdd(o + 2, v.z);
        atomicAdd(o + 3, v.w);
    }
}

static inline size_t align16(size_t x) { return (x + 15) & ~(size_t)15; }

extern "C" void kernel_launch(void* const* d_in, const int* in_sizes, int n_in,
                              void* d_out, int out_size, void* d_ws, size_t ws_size,
                              hipStream_t stream)
{
    const float* x  = (const float*)d_in[0];
    const float* W0 = (const float*)d_in[1];
    const float* b0 = (const float*)d_in[2];
    const float* W1 = (const float*)d_in[3];
    const float* b1 = (const float*)d_in[4];
    const int* eidx = (const int*)d_in[5];
    const int* etyp = (const int*)d_in[6];

    const int M = in_sizes[0] / DIM;   // 50000
    const int E = in_sizes[6];         // 800000
    const int* src = eidx;
    const int* dst = eidx + E;
    float* out = (float*)d_out;

    const size_t plane = (size_t)M * DIM;
    const size_t wbytes = (size_t)N_REL * DIM * DIM * 2;

    const size_t need = align16(plane * 2)              // h1b
                      + align16(plane * 2)              // xb
                      + 2 * align16(wbytes)             // Wt0b, Wt1b
                      + align16((size_t)(M + 1) * 4)    // rowptr
                      + 2 * align16((size_t)M * 4)      // cnt, cursor
                      + align16((size_t)E * 4)          // ep
                      + align16((size_t)N_REL * plane * 2);  // yall

    if (M < 65536 && ws_size >= need) {
        char* ws = (char*)d_ws;
        size_t off = 0;
        unsigned short* h1b = (unsigned short*)(ws + off); off = align16(off + plane * 2);
        unsigned short* xb  = (unsigned short*)(ws + off); off = align16(off + plane * 2);
        unsigned short* Wt0b = (unsigned short*)(ws + off); off = align16(off + wbytes);
        unsigned short* Wt1b = (unsigned short*)(ws + off); off = align16(off + wbytes);
        int* rowptr = (int*)(ws + off); off = align16(off + (size_t)(M + 1) * 4);
        int* cnt    = (int*)(ws + off); off = align16(off + (size_t)M * 4);
        int* cursor = (int*)(ws + off); off = align16(off + (size_t)M * 4);
        unsigned* ep = (unsigned*)(ws + off); off = align16(off + (size_t)E * 4);
        unsigned short* yall = (unsigned short*)(ws + off);

        // CSR build (shared by both layers)
        hipMemsetAsync(cnt, 0, (size_t)M * 4, stream);
        count_dst<<<(E + 255) / 256, 256, 0, stream>>>(dst, E, cnt);
        scan_counts<<<1, 1024, 0, stream>>>(cnt, M, rowptr, cursor);
        fill_edges<<<(E + 255) / 256, 256, 0, stream>>>(src, dst, etyp, E, cursor, ep);

        // prep: casts / transposes
        cast_f32_bf16<<<(int)((plane / 4 + 255) / 256), 256, 0, stream>>>(
            x, xb, (int)(plane / 4));
        transpose_cast_w<<<dim3(8, 8, N_REL), dim3(32, 8), 0, stream>>>(W0, Wt0b);
        transpose_cast_w<<<dim3(8, 8, N_REL), dim3(32, 8), 0, stream>>>(W1, Wt1b);

        const dim3 gblk(256), ggrid((M + 127) / 128, DIM / 128, N_REL);
        const int ablk = 256;
        const int agrid = (int)(((size_t)M * 64 + ablk - 1) / ablk);

        // layer 1
        gemm_mfma_bias_relu<<<ggrid, gblk, 0, stream>>>(xb, Wt0b, b0, yall, M);
        aggregate_bf16<unsigned short><<<agrid, ablk, 0, stream>>>(yall, ep, rowptr, h1b, M);
        // layer 2
        gemm_mfma_bias_relu<<<ggrid, gblk, 0, stream>>>(h1b, Wt1b, b1, yall, M);
        aggregate_bf16<float><<<agrid, ablk, 0, stream>>>(yall, ep, rowptr, out, M);
    } else {
        // fallback: fp32 per-relation GEMM + atomic scatter
        float* h1 = (float*)d_ws;
        float* y  = (float*)d_ws + plane;
        const dim3 gblk(256), ggrid((M + 127) / 128, DIM / 128);
        hipMemsetAsync(h1, 0, plane * 4, stream);
        for (int r = 0; r < N_REL; r++) {
            gemm_bias_relu_f32<<<ggrid, gblk, 0, stream>>>(
                x, W0 + (size_t)r * DIM * DIM, b0, y, M);
            scatter_rel<<<1024, 256, 0, stream>>>(y, src, dst, etyp, r, h1, E);
        }
        hipMemsetAsync(out, 0, plane * 4, stream);
        for (int r = 0; r < N_REL; r++) {
            gemm_bias_relu_f32<<<ggrid, gblk, 0, stream>>>(
                h1, W1 + (size_t)r * DIM * DIM, b1, y, M);
            scatter_rel<<<1024, 256, 0, stream>>>(y, src, dst, etyp, r, out, E);
        }
    }
}